// Round 1
// baseline (3123.136 us; speedup 1.0000x reference)
//
#include <hip/hip_runtime.h>
#include <cstdint>

// ViMBlock: RMSNorm -> in_linear(+sigmoid gate split) -> dwconv(K=3) ->
// pointwise -> bidir diagonal SSM (scan) -> out-proj(+gate) -> out_linear(+residual)
// B=4, L=4096, D=1024, N=64, K=3. All fp32 this round (correctness baseline).

#define L_SEQ 4096
#define D_DIM 1024
#define B_SZ 4
#define M_TOK (B_SZ * L_SEQ)   // 16384 tokens

// ---------------- RMSNorm ----------------
__global__ __launch_bounds__(256) void rmsnorm_kernel(
    const float* __restrict__ T, const float* __restrict__ scale,
    float* __restrict__ Tn) {
  int tok = blockIdx.x;
  int t = threadIdx.x;                     // 256 threads, 4 floats each
  const float4* row = (const float4*)(T + (size_t)tok * D_DIM);
  float4 v = row[t];
  float ss = v.x*v.x + v.y*v.y + v.z*v.z + v.w*v.w;
  #pragma unroll
  for (int off = 32; off > 0; off >>= 1) ss += __shfl_down(ss, off);
  __shared__ float part[4];
  if ((t & 63) == 0) part[t >> 6] = ss;
  __syncthreads();
  float total = part[0] + part[1] + part[2] + part[3];
  float rinv = rsqrtf(total * (1.0f / D_DIM) + 1e-6f);
  const float4* sc4 = (const float4*)scale;
  float4 s = sc4[t];
  float4 o;
  o.x = v.x * rinv * s.x; o.y = v.y * rinv * s.y;
  o.z = v.z * rinv * s.z; o.w = v.w * rinv * s.w;
  ((float4*)(Tn + (size_t)tok * D_DIM))[t] = o;
}

// ---------------- prepack SSM weights into contiguous (rows x K) ----------------
// Wu: 128 rows x 1024 (f_win on top of b_win)   [for u = x_conv @ Wu^T]
// Wy: 1024 rows x 128 (cols 0:64 = f_wout[d,:], 64:128 = b_wout[d,:])
__global__ void prepack_kernel(
    const float* __restrict__ f_win, const float* __restrict__ b_win,
    const float* __restrict__ f_wout, const float* __restrict__ b_wout,
    float* __restrict__ Wu, float* __restrict__ Wy) {
  int i = blockIdx.x * blockDim.x + threadIdx.x;
  if (i < 128 * D_DIM) {
    int n = i >> 10, k = i & (D_DIM - 1);
    Wu[i] = (n < 64) ? f_win[n * D_DIM + k] : b_win[(n - 64) * D_DIM + k];
    int d = i >> 7, kk = i & 127;
    Wy[i] = (kk < 64) ? f_wout[d * 64 + kk] : b_wout[d * 64 + (kk - 64)];
  }
}

// ---------------- generic tiled fp32 GEMM: C = A @ B^T (+epilogue) ----------------
// A: (M,Kt) row-major; Bw: (N,Kt) row-major. 64x64 tile, 256 thr, 4x4/thr.
// mode 0: out[m*N+n] = v (+bias[n] if bias)
// mode 1: split (N=2048): n<1024 -> out[m*1024+n]=v ; else aux1[m*1024+n-1024]=sigmoid(v)
// mode 2: out[m*N+n] = v * aux0[m*N+n]            (gate multiply)
// mode 3: out[m*N+n] = v (+bias) + aux0[m*N+n]    (residual)
#define BM 64
#define BN 64
#define BK 16
__global__ __launch_bounds__(256) void gemm_bt_kernel(
    const float* __restrict__ A, const float* __restrict__ Bw,
    const float* __restrict__ bias, float* __restrict__ out,
    int M, int N, int Kt, int mode,
    const float* __restrict__ aux0, float* __restrict__ aux1) {
  __shared__ float As[BK][BM + 1];
  __shared__ float Bs[BK][BN + 1];
  int tid = threadIdx.x;
  int tx = tid & 15, ty = tid >> 4;
  int bm = blockIdx.x * BM, bn = blockIdx.y * BN;
  int lr = tid >> 2;          // 0..63: row within tile
  int lc = (tid & 3) * 4;     // k offset {0,4,8,12}
  const float* Ap = A  + (size_t)(bm + lr) * Kt + lc;
  const float* Bp = Bw + (size_t)(bn + lr) * Kt + lc;
  float acc[4][4] = {};
  for (int k0 = 0; k0 < Kt; k0 += BK) {
    float4 av = *(const float4*)(Ap + k0);
    float4 bv = *(const float4*)(Bp + k0);
    As[lc+0][lr] = av.x; As[lc+1][lr] = av.y; As[lc+2][lr] = av.z; As[lc+3][lr] = av.w;
    Bs[lc+0][lr] = bv.x; Bs[lc+1][lr] = bv.y; Bs[lc+2][lr] = bv.z; Bs[lc+3][lr] = bv.w;
    __syncthreads();
    #pragma unroll
    for (int k = 0; k < BK; ++k) {
      float ar[4], br[4];
      #pragma unroll
      for (int i = 0; i < 4; ++i) ar[i] = As[k][ty*4 + i];
      #pragma unroll
      for (int j = 0; j < 4; ++j) br[j] = Bs[k][tx*4 + j];
      #pragma unroll
      for (int i = 0; i < 4; ++i)
        #pragma unroll
        for (int j = 0; j < 4; ++j)
          acc[i][j] += ar[i] * br[j];
    }
    __syncthreads();
  }
  #pragma unroll
  for (int i = 0; i < 4; ++i) {
    int m = bm + ty*4 + i;
    #pragma unroll
    for (int j = 0; j < 4; ++j) {
      int n = bn + tx*4 + j;
      float v = acc[i][j];
      if (bias) v += bias[n];
      if (mode == 0) {
        out[(size_t)m * N + n] = v;
      } else if (mode == 1) {
        if (n < D_DIM) out[(size_t)m * D_DIM + n] = v;
        else aux1[(size_t)m * D_DIM + (n - D_DIM)] = 1.0f / (1.0f + expf(-v));
      } else if (mode == 2) {
        out[(size_t)m * N + n] = v * aux0[(size_t)m * N + n];
      } else {
        out[(size_t)m * N + n] = v + aux0[(size_t)m * N + n];
      }
    }
  }
}

// ---------------- depthwise conv1d K=3, zero pad, along L ----------------
__global__ __launch_bounds__(256) void dwconv_kernel(
    const float* __restrict__ x, const float* __restrict__ w,
    const float* __restrict__ b, float* __restrict__ out) {
  size_t idx = (size_t)blockIdx.x * 256 + threadIdx.x;   // over B*L*D
  int d = (int)(idx & (D_DIM - 1));
  int l = (int)((idx >> 10) & (L_SEQ - 1));
  float w0 = w[d*3 + 0], w1 = w[d*3 + 1], w2 = w[d*3 + 2];
  float acc = b[d] + w1 * x[idx];
  if (l > 0)         acc += w0 * x[idx - D_DIM];
  if (l < L_SEQ - 1) acc += w2 * x[idx + D_DIM];
  out[idx] = acc;
}

// ---------------- bidirectional diagonal SSM scan ----------------
// u,y: (M_TOK, 128) — cols 0:64 fwd, 64:128 bwd. 8 blocks x 64 thr:
// block = dir*4 + b ; thread = n. Sequential over L with 8-deep prefetch.
__global__ __launch_bounds__(64) void scan_kernel(
    const float* __restrict__ u, float* __restrict__ y,
    const float* __restrict__ f_logA, const float* __restrict__ f_B,
    const float* __restrict__ f_C, const float* __restrict__ f_logdt,
    const float* __restrict__ b_logA, const float* __restrict__ b_B,
    const float* __restrict__ b_C, const float* __restrict__ b_logdt) {
  int n = threadIdx.x;
  int dir = blockIdx.x >> 2;
  int b = blockIdx.x & 3;
  const float* logA  = dir ? b_logA  : f_logA;
  const float* Bp    = dir ? b_B     : f_B;
  const float* Cp    = dir ? b_C     : f_C;
  const float* logdt = dir ? b_logdt : f_logdt;
  float dt = expf(logdt[0]);
  float Aa = -expf(logA[n]);
  float Abar = expf(Aa * dt);
  float frac = (fabsf(Aa) < 1e-6f) ? dt : (Abar - 1.0f) / Aa;
  float Bbar = frac * Bp[n];
  float Cc = Cp[n];
  int col = dir * 64 + n;
  size_t base = (size_t)b * L_SEQ * 128 + col;
  float h = 0.0f;
  if (dir == 0) {
    for (int l0 = 0; l0 < L_SEQ; l0 += 8) {
      float uv[8];
      #pragma unroll
      for (int i = 0; i < 8; ++i) uv[i] = u[base + (size_t)(l0 + i) * 128];
      #pragma unroll
      for (int i = 0; i < 8; ++i) {
        h = h * Abar + uv[i] * Bbar;
        y[base + (size_t)(l0 + i) * 128] = h * Cc;
      }
    }
  } else {
    for (int l0 = L_SEQ - 1; l0 >= 0; l0 -= 8) {
      float uv[8];
      #pragma unroll
      for (int i = 0; i < 8; ++i) uv[i] = u[base + (size_t)(l0 - i) * 128];
      #pragma unroll
      for (int i = 0; i < 8; ++i) {
        h = h * Abar + uv[i] * Bbar;
        y[base + (size_t)(l0 - i) * 128] = h * Cc;
      }
    }
  }
}

extern "C" void kernel_launch(void* const* d_in, const int* in_sizes, int n_in,
                              void* d_out, int out_size, void* d_ws, size_t ws_size,
                              hipStream_t stream) {
  const float* T         = (const float*)d_in[0];
  const float* norm_scale= (const float*)d_in[1];
  const float* in_w      = (const float*)d_in[2];
  const float* in_b      = (const float*)d_in[3];
  const float* dw_w      = (const float*)d_in[4];
  const float* dw_b      = (const float*)d_in[5];
  const float* pw_w      = (const float*)d_in[6];
  const float* pw_b      = (const float*)d_in[7];
  const float* f_win     = (const float*)d_in[8];
  const float* f_wout    = (const float*)d_in[9];
  const float* f_logA    = (const float*)d_in[10];
  const float* f_B       = (const float*)d_in[11];
  const float* f_C       = (const float*)d_in[12];
  const float* f_logdt   = (const float*)d_in[13];
  const float* b_win     = (const float*)d_in[14];
  const float* b_wout    = (const float*)d_in[15];
  const float* b_logA    = (const float*)d_in[16];
  const float* b_B       = (const float*)d_in[17];
  const float* b_C       = (const float*)d_in[18];
  const float* b_logdt   = (const float*)d_in[19];
  const float* out_w     = (const float*)d_in[20];
  const float* out_b     = (const float*)d_in[21];
  float* out = (float*)d_out;

  // workspace layout (floats). Total = 3*16.78M + 2*2.10M + 2*0.13M
  //   = 54,788,096 floats = ~209 MB
  float* ws = (float*)d_ws;
  const size_t BIG = (size_t)M_TOK * D_DIM;
  float* buf0 = ws;                      // Tn -> dwconv-out -> y_gated
  float* buf1 = ws + BIG;                // x -> x_conv
  float* buf2 = ws + 2 * BIG;            // gate
  float* u    = ws + 3 * BIG;            // (M,128)
  float* yb   = u + (size_t)M_TOK * 128; // (M,128)
  float* Wu   = yb + (size_t)M_TOK * 128;        // 128 x 1024
  float* Wy   = Wu + (size_t)128 * D_DIM;        // 1024 x 128

  // 1. RMSNorm: T -> buf0
  rmsnorm_kernel<<<M_TOK, 256, 0, stream>>>(T, norm_scale, buf0);
  // 2. prepack SSM weights
  prepack_kernel<<<(128 * D_DIM) / 256, 256, 0, stream>>>(f_win, b_win, f_wout, b_wout, Wu, Wy);
  // 3. in_linear: buf0 @ in_w^T + in_b -> x(buf1), gate(buf2)
  {
    dim3 g(M_TOK / BM, (2 * D_DIM) / BN);
    gemm_bt_kernel<<<g, 256, 0, stream>>>(buf0, in_w, in_b, buf1,
                                          M_TOK, 2 * D_DIM, D_DIM, 1, nullptr, buf2);
  }
  // 4. depthwise conv: buf1 -> buf0
  dwconv_kernel<<<((size_t)M_TOK * D_DIM) / 256, 256, 0, stream>>>(buf1, dw_w, dw_b, buf0);
  // 5. pointwise: buf0 @ pw_w^T + pw_b -> buf1 (x_conv)
  {
    dim3 g(M_TOK / BM, D_DIM / BN);
    gemm_bt_kernel<<<g, 256, 0, stream>>>(buf0, pw_w, pw_b, buf1,
                                          M_TOK, D_DIM, D_DIM, 0, nullptr, nullptr);
  }
  // 6. SSM in-proj: buf1 @ Wu^T -> u (M,128)
  {
    dim3 g(M_TOK / BM, 128 / BN);
    gemm_bt_kernel<<<g, 256, 0, stream>>>(buf1, Wu, nullptr, u,
                                          M_TOK, 128, D_DIM, 0, nullptr, nullptr);
  }
  // 7. bidirectional scan: u -> yb
  scan_kernel<<<8, 64, 0, stream>>>(u, yb, f_logA, f_B, f_C, f_logdt,
                                    b_logA, b_B, b_C, b_logdt);
  // 8. SSM out-proj + gate: yb @ Wy^T * gate -> buf0 (y_gated)
  {
    dim3 g(M_TOK / BM, D_DIM / BN);
    gemm_bt_kernel<<<g, 256, 0, stream>>>(yb, Wy, nullptr, buf0,
                                          M_TOK, D_DIM, 128, 2, buf2, nullptr);
  }
  // 9. out_linear + residual: buf0 @ out_w^T + out_b + T -> out
  {
    dim3 g(M_TOK / BM, D_DIM / BN);
    gemm_bt_kernel<<<g, 256, 0, stream>>>(buf0, out_w, out_b, out,
                                          M_TOK, D_DIM, D_DIM, 3, T, nullptr);
  }
}

// Round 2
// 818.400 us; speedup vs baseline: 3.8161x; 3.8161x over previous
//
#include <hip/hip_runtime.h>
#include <cstdint>

// ViMBlock bf16-MFMA version. B=4, L=4096, D=1024, N=64, K=3.
// GEMMs: m97 structure — 128x128 tile, 16x16x32 bf16 MFMA, global_load_lds(16B).

#define L_SEQ 4096
#define D_DIM 1024
#define B_SZ 4
#define M_TOK (B_SZ * L_SEQ)   // 16384 tokens

typedef short bf16x8 __attribute__((ext_vector_type(8)));
typedef float floatx4 __attribute__((ext_vector_type(4)));

__device__ inline unsigned short f2bf(float f) {
  union { float f; unsigned int u; } v; v.f = f;
  unsigned int r = v.u + 0x7FFFu + ((v.u >> 16) & 1u);
  return (unsigned short)(r >> 16);
}
__device__ inline float bf2f(unsigned short h) {
  union { unsigned int u; float f; } v; v.u = ((unsigned int)h) << 16;
  return v.f;
}

__device__ inline void load_lds16(const unsigned short* g, unsigned short* l) {
  __builtin_amdgcn_global_load_lds(
      (const __attribute__((address_space(1))) unsigned int*)g,
      (__attribute__((address_space(3))) unsigned int*)l, 16, 0, 0);
}

// ---------------- RMSNorm: fp32 in -> bf16 out ----------------
__global__ __launch_bounds__(256) void rmsnorm_kernel(
    const float* __restrict__ T, const float* __restrict__ scale,
    unsigned short* __restrict__ Tn) {
  int tok = blockIdx.x;
  int t = threadIdx.x;                     // 256 threads, 4 floats each
  const float4* row = (const float4*)(T + (size_t)tok * D_DIM);
  float4 v = row[t];
  float ss = v.x*v.x + v.y*v.y + v.z*v.z + v.w*v.w;
  #pragma unroll
  for (int off = 32; off > 0; off >>= 1) ss += __shfl_down(ss, off);
  __shared__ float part[4];
  if ((t & 63) == 0) part[t >> 6] = ss;
  __syncthreads();
  float total = part[0] + part[1] + part[2] + part[3];
  float rinv = rsqrtf(total * (1.0f / D_DIM) + 1e-6f);
  const float4* sc4 = (const float4*)scale;
  float4 s = sc4[t];
  ushort4 o;
  o.x = f2bf(v.x * rinv * s.x); o.y = f2bf(v.y * rinv * s.y);
  o.z = f2bf(v.z * rinv * s.z); o.w = f2bf(v.w * rinv * s.w);
  ((ushort4*)(Tn + (size_t)tok * D_DIM))[t] = o;
}

// ---------------- fp32 -> bf16 convert (n4 = n/4) ----------------
__global__ __launch_bounds__(256) void f2bf_vec_kernel(
    const float* __restrict__ in, unsigned short* __restrict__ out, int n4) {
  int i = blockIdx.x * 256 + threadIdx.x;
  if (i < n4) {
    float4 v = ((const float4*)in)[i];
    ushort4 o; o.x = f2bf(v.x); o.y = f2bf(v.y); o.z = f2bf(v.z); o.w = f2bf(v.w);
    ((ushort4*)out)[i] = o;
  }
}

// ---------------- prepack SSM weights -> bf16 ----------------
// Wu: 128 rows x 1024 (f_win ; b_win).  Wy: 1024 rows x 128 (f_wout | b_wout).
__global__ void prepack_kernel(
    const float* __restrict__ f_win, const float* __restrict__ b_win,
    const float* __restrict__ f_wout, const float* __restrict__ b_wout,
    unsigned short* __restrict__ Wu, unsigned short* __restrict__ Wy) {
  int i = blockIdx.x * blockDim.x + threadIdx.x;
  if (i < 128 * D_DIM) {
    int n = i >> 10, k = i & (D_DIM - 1);
    Wu[i] = f2bf((n < 64) ? f_win[n * D_DIM + k] : b_win[(n - 64) * D_DIM + k]);
    int d = i >> 7, kk = i & 127;
    Wy[i] = f2bf((kk < 64) ? f_wout[d * 64 + kk] : b_wout[d * 64 + (kk - 64)]);
  }
}

// ---------------- bf16 MFMA GEMM: C = A @ Bw^T (+epilogue) ----------------
// A: (M,Kt) bf16 row-major; Bw: (N,Kt) bf16 row-major. 128x128 tile, 256 thr
// (4 waves in 2x2 of 64x64), 16x16x32 MFMA, 4x4 acc frags per wave.
// MODE 0: out = v (+bias[n])                (OUT_T = ushort or float)
// MODE 1: N=2048 split: n<1024 -> out(bf16)=v+bias ; else aux1(f32)=sigmoid(v+bias)
// MODE 2: out(bf16) = v * aux0[m*N+n]       (gate multiply, aux0 fp32)
// MODE 3: out(f32)  = v + bias[n] + aux0[m*N+n]   (residual)
template<int MODE, typename OUT_T>
__global__ __launch_bounds__(256) void gemm_mfma_kernel(
    const unsigned short* __restrict__ A, const unsigned short* __restrict__ Bw,
    const float* __restrict__ bias, OUT_T* __restrict__ out,
    int M, int N, int Kt,
    const float* __restrict__ aux0, float* __restrict__ aux1) {
  __shared__ unsigned short As[128 * 32];
  __shared__ unsigned short Bs[128 * 32];
  int tid = threadIdx.x;
  int wave = tid >> 6, lane = tid & 63;
  int quad = lane >> 4, lrow = lane & 15;
  int bm = blockIdx.x * 128, bn = blockIdx.y * 128;
  int wm = (wave & 1) * 64, wn = (wave >> 1) * 64;

  // staging: chunk = c*256 + tid; row = chunk>>2 (4x16B per 64B row), col8 = (chunk&3)*8
  int r0 = tid >> 2;
  int c8 = (tid & 3) * 8;
  const unsigned short* Ag0 = A  + (size_t)(bm + r0) * Kt + c8;
  const unsigned short* Ag1 = A  + (size_t)(bm + 64 + r0) * Kt + c8;
  const unsigned short* Bg0 = Bw + (size_t)(bn + r0) * Kt + c8;
  const unsigned short* Bg1 = Bw + (size_t)(bn + 64 + r0) * Kt + c8;
  // wave-uniform LDS bases (HW adds lane*16B)
  unsigned short* Al0 = As + (size_t)(wave * 64) * 8;
  unsigned short* Al1 = As + (size_t)(256 + wave * 64) * 8;
  unsigned short* Bl0 = Bs + (size_t)(wave * 64) * 8;
  unsigned short* Bl1 = Bs + (size_t)(256 + wave * 64) * 8;

  floatx4 acc[4][4] = {};
  for (int k0 = 0; k0 < Kt; k0 += 32) {
    load_lds16(Ag0 + k0, Al0);
    load_lds16(Ag1 + k0, Al1);
    load_lds16(Bg0 + k0, Bl0);
    load_lds16(Bg1 + k0, Bl1);
    __syncthreads();   // compiler emits vmcnt(0) drain before s_barrier
    bf16x8 af[4], bfr[4];
    #pragma unroll
    for (int mi = 0; mi < 4; ++mi)
      af[mi] = *(const bf16x8*)(As + (wm + mi * 16 + lrow) * 32 + quad * 8);
    #pragma unroll
    for (int ni = 0; ni < 4; ++ni)
      bfr[ni] = *(const bf16x8*)(Bs + (wn + ni * 16 + lrow) * 32 + quad * 8);
    #pragma unroll
    for (int mi = 0; mi < 4; ++mi)
      #pragma unroll
      for (int ni = 0; ni < 4; ++ni)
        acc[mi][ni] = __builtin_amdgcn_mfma_f32_16x16x32_bf16(
            af[mi], bfr[ni], acc[mi][ni], 0, 0, 0);
    __syncthreads();
  }

  // epilogue: C/D layout col=lane&15, row=quad*4+reg  [m89-verified]
  #pragma unroll
  for (int mi = 0; mi < 4; ++mi) {
    #pragma unroll
    for (int ni = 0; ni < 4; ++ni) {
      #pragma unroll
      for (int r = 0; r < 4; ++r) {
        int m = bm + wm + mi * 16 + quad * 4 + r;
        int n = bn + wn + ni * 16 + lrow;
        float v = acc[mi][ni][r];
        if (MODE == 0) {
          if (bias) v += bias[n];
          if (sizeof(OUT_T) == 2) out[(size_t)m * N + n] = (OUT_T)f2bf(v);
          else                    out[(size_t)m * N + n] = (OUT_T)v;
        } else if (MODE == 1) {
          if (bias) v += bias[n];
          if (n < D_DIM) ((unsigned short*)out)[(size_t)m * D_DIM + n] = f2bf(v);
          else aux1[(size_t)m * D_DIM + (n - D_DIM)] = 1.0f / (1.0f + expf(-v));
        } else if (MODE == 2) {
          v *= aux0[(size_t)m * N + n];
          ((unsigned short*)out)[(size_t)m * N + n] = f2bf(v);
        } else {
          if (bias) v += bias[n];
          v += aux0[(size_t)m * N + n];
          ((float*)out)[(size_t)m * N + n] = v;
        }
      }
    }
  }
}

// ---------------- depthwise conv1d K=3 (bf16 in/out, fp32 math) ----------------
// thread handles 8 consecutive channels (16B loads/stores)
__global__ __launch_bounds__(256) void dwconv_kernel(
    const unsigned short* __restrict__ x, const float* __restrict__ w,
    const float* __restrict__ b, unsigned short* __restrict__ out) {
  size_t i8 = (size_t)blockIdx.x * 256 + threadIdx.x;    // over M*D/8
  int d8 = (int)(i8 & (D_DIM / 8 - 1));
  size_t tok = i8 >> 7;
  int l = (int)(tok & (L_SEQ - 1));
  int d0 = d8 * 8;
  size_t base = tok * D_DIM + d0;
  bf16x8 cur = *(const bf16x8*)(x + base);
  float acc[8];
  #pragma unroll
  for (int j = 0; j < 8; ++j) {
    int d = d0 + j;
    acc[j] = b[d] + w[d * 3 + 1] * bf2f((unsigned short)cur[j]);
  }
  if (l > 0) {
    bf16x8 prv = *(const bf16x8*)(x + base - D_DIM);
    #pragma unroll
    for (int j = 0; j < 8; ++j) acc[j] += w[(d0 + j) * 3 + 0] * bf2f((unsigned short)prv[j]);
  }
  if (l < L_SEQ - 1) {
    bf16x8 nxt = *(const bf16x8*)(x + base + D_DIM);
    #pragma unroll
    for (int j = 0; j < 8; ++j) acc[j] += w[(d0 + j) * 3 + 2] * bf2f((unsigned short)nxt[j]);
  }
  bf16x8 o;
  #pragma unroll
  for (int j = 0; j < 8; ++j) o[j] = (short)f2bf(acc[j]);
  *(bf16x8*)(out + base) = o;
}

// ---------------- bidirectional diagonal SSM scan (u fp32 -> y bf16) ----------------
__global__ __launch_bounds__(64) void scan_kernel(
    const float* __restrict__ u, unsigned short* __restrict__ y,
    const float* __restrict__ f_logA, const float* __restrict__ f_B,
    const float* __restrict__ f_C, const float* __restrict__ f_logdt,
    const float* __restrict__ b_logA, const float* __restrict__ b_B,
    const float* __restrict__ b_C, const float* __restrict__ b_logdt) {
  int n = threadIdx.x;
  int dir = blockIdx.x >> 2;
  int b = blockIdx.x & 3;
  const float* logA  = dir ? b_logA  : f_logA;
  const float* Bp    = dir ? b_B     : f_B;
  const float* Cp    = dir ? b_C     : f_C;
  const float* logdt = dir ? b_logdt : f_logdt;
  float dt = expf(logdt[0]);
  float Aa = -expf(logA[n]);
  float Abar = expf(Aa * dt);
  float frac = (fabsf(Aa) < 1e-6f) ? dt : (Abar - 1.0f) / Aa;
  float Bbar = frac * Bp[n];
  float Cc = Cp[n];
  int col = dir * 64 + n;
  size_t base = (size_t)b * L_SEQ * 128 + col;
  float h = 0.0f;
  if (dir == 0) {
    for (int l0 = 0; l0 < L_SEQ; l0 += 8) {
      float uv[8];
      #pragma unroll
      for (int i = 0; i < 8; ++i) uv[i] = u[base + (size_t)(l0 + i) * 128];
      #pragma unroll
      for (int i = 0; i < 8; ++i) {
        h = h * Abar + uv[i] * Bbar;
        y[base + (size_t)(l0 + i) * 128] = f2bf(h * Cc);
      }
    }
  } else {
    for (int l0 = L_SEQ - 1; l0 >= 0; l0 -= 8) {
      float uv[8];
      #pragma unroll
      for (int i = 0; i < 8; ++i) uv[i] = u[base + (size_t)(l0 - i) * 128];
      #pragma unroll
      for (int i = 0; i < 8; ++i) {
        h = h * Abar + uv[i] * Bbar;
        y[base + (size_t)(l0 - i) * 128] = f2bf(h * Cc);
      }
    }
  }
}

extern "C" void kernel_launch(void* const* d_in, const int* in_sizes, int n_in,
                              void* d_out, int out_size, void* d_ws, size_t ws_size,
                              hipStream_t stream) {
  const float* T         = (const float*)d_in[0];
  const float* norm_scale= (const float*)d_in[1];
  const float* in_w      = (const float*)d_in[2];
  const float* in_b      = (const float*)d_in[3];
  const float* dw_w      = (const float*)d_in[4];
  const float* dw_b      = (const float*)d_in[5];
  const float* pw_w      = (const float*)d_in[6];
  const float* pw_b      = (const float*)d_in[7];
  const float* f_win     = (const float*)d_in[8];
  const float* f_wout    = (const float*)d_in[9];
  const float* f_logA    = (const float*)d_in[10];
  const float* f_B       = (const float*)d_in[11];
  const float* f_C       = (const float*)d_in[12];
  const float* f_logdt   = (const float*)d_in[13];
  const float* b_win     = (const float*)d_in[14];
  const float* b_wout    = (const float*)d_in[15];
  const float* b_logA    = (const float*)d_in[16];
  const float* b_B       = (const float*)d_in[17];
  const float* b_C       = (const float*)d_in[18];
  const float* b_logdt   = (const float*)d_in[19];
  const float* out_w     = (const float*)d_in[20];
  const float* out_b     = (const float*)d_in[21];
  float* out = (float*)d_out;

  // workspace layout (bytes):
  //   gate  f32  64MB | bufA bf16 32MB | bufB bf16 32MB | u f32 8MB | y bf16 4MB
  //   w_in 4MB | w_pw 2MB | w_out 2MB | Wu 256KB | Wy 256KB   (~148.5MB total)
  char* ws = (char*)d_ws;
  const size_t MD = (size_t)M_TOK * D_DIM;
  float*          gate  = (float*)ws;                       ws += MD * 4;
  unsigned short* bufA  = (unsigned short*)ws;              ws += MD * 2;
  unsigned short* bufB  = (unsigned short*)ws;              ws += MD * 2;
  float*          u     = (float*)ws;                       ws += (size_t)M_TOK * 128 * 4;
  unsigned short* ybuf  = (unsigned short*)ws;              ws += (size_t)M_TOK * 128 * 2;
  unsigned short* w_in  = (unsigned short*)ws;              ws += (size_t)2 * D_DIM * D_DIM * 2;
  unsigned short* w_pw  = (unsigned short*)ws;              ws += (size_t)D_DIM * D_DIM * 2;
  unsigned short* w_out = (unsigned short*)ws;              ws += (size_t)D_DIM * D_DIM * 2;
  unsigned short* Wu    = (unsigned short*)ws;              ws += (size_t)128 * D_DIM * 2;
  unsigned short* Wy    = (unsigned short*)ws;

  // 0. weight conversion / prepack
  f2bf_vec_kernel<<<(2 * D_DIM * D_DIM / 4 + 255) / 256, 256, 0, stream>>>(in_w, w_in, 2 * D_DIM * D_DIM / 4);
  f2bf_vec_kernel<<<(D_DIM * D_DIM / 4 + 255) / 256, 256, 0, stream>>>(pw_w, w_pw, D_DIM * D_DIM / 4);
  f2bf_vec_kernel<<<(D_DIM * D_DIM / 4 + 255) / 256, 256, 0, stream>>>(out_w, w_out, D_DIM * D_DIM / 4);
  prepack_kernel<<<(128 * D_DIM) / 256, 256, 0, stream>>>(f_win, b_win, f_wout, b_wout, Wu, Wy);
  // 1. RMSNorm: T -> bufA (bf16)
  rmsnorm_kernel<<<M_TOK, 256, 0, stream>>>(T, norm_scale, bufA);
  // 2. in_linear: bufA @ w_in^T + in_b -> x(bufB bf16), gate(f32)
  {
    dim3 g(M_TOK / 128, (2 * D_DIM) / 128);
    gemm_mfma_kernel<1, unsigned short><<<g, 256, 0, stream>>>(
        bufA, w_in, in_b, bufB, M_TOK, 2 * D_DIM, D_DIM, nullptr, gate);
  }
  // 3. depthwise conv: bufB -> bufA
  dwconv_kernel<<<(MD / 8) / 256, 256, 0, stream>>>(bufB, dw_w, dw_b, bufA);
  // 4. pointwise: bufA @ w_pw^T + pw_b -> bufB (x_conv bf16)
  {
    dim3 g(M_TOK / 128, D_DIM / 128);
    gemm_mfma_kernel<0, unsigned short><<<g, 256, 0, stream>>>(
        bufA, w_pw, pw_b, bufB, M_TOK, D_DIM, D_DIM, nullptr, nullptr);
  }
  // 5. SSM in-proj: bufB @ Wu^T -> u (f32, M x 128)
  {
    dim3 g(M_TOK / 128, 1);
    gemm_mfma_kernel<0, float><<<g, 256, 0, stream>>>(
        bufB, Wu, nullptr, u, M_TOK, 128, D_DIM, nullptr, nullptr);
  }
  // 6. bidirectional scan: u -> ybuf (bf16)
  scan_kernel<<<8, 64, 0, stream>>>(u, ybuf, f_logA, f_B, f_C, f_logdt,
                                    b_logA, b_B, b_C, b_logdt);
  // 7. SSM out-proj + gate: ybuf @ Wy^T * gate -> bufA (bf16)
  {
    dim3 g(M_TOK / 128, D_DIM / 128);
    gemm_mfma_kernel<2, unsigned short><<<g, 256, 0, stream>>>(
        ybuf, Wy, nullptr, bufA, M_TOK, D_DIM, 128, gate, nullptr);
  }
  // 8. out_linear + residual: bufA @ w_out^T + out_b + T -> out (f32)
  {
    dim3 g(M_TOK / 128, D_DIM / 128);
    gemm_mfma_kernel<3, float><<<g, 256, 0, stream>>>(
        bufA, w_out, out_b, out, M_TOK, D_DIM, D_DIM, T, nullptr);
  }
}

// Round 3
// 642.998 us; speedup vs baseline: 4.8571x; 1.2728x over previous
//
#include <hip/hip_runtime.h>
#include <cstdint>

// ViMBlock bf16-MFMA + chunked parallel scan. B=4, L=4096, D=1024, N=64, K=3.

#define L_SEQ 4096
#define D_DIM 1024
#define B_SZ 4
#define M_TOK (B_SZ * L_SEQ)   // 16384 tokens
#define CHUNKS 64
#define CLEN (L_SEQ / CHUNKS)  // 64

typedef short bf16x8 __attribute__((ext_vector_type(8)));
typedef float floatx4 __attribute__((ext_vector_type(4)));

__device__ inline unsigned short f2bf(float f) {
  union { float f; unsigned int u; } v; v.f = f;
  unsigned int r = v.u + 0x7FFFu + ((v.u >> 16) & 1u);
  return (unsigned short)(r >> 16);
}
__device__ inline float bf2f(unsigned short h) {
  union { unsigned int u; float f; } v; v.u = ((unsigned int)h) << 16;
  return v.f;
}

__device__ inline void load_lds16(const unsigned short* g, unsigned short* l) {
  __builtin_amdgcn_global_load_lds(
      (const __attribute__((address_space(1))) unsigned int*)g,
      (__attribute__((address_space(3))) unsigned int*)l, 16, 0, 0);
}

// ---------------- RMSNorm: fp32 in -> bf16 out ----------------
__global__ __launch_bounds__(256) void rmsnorm_kernel(
    const float* __restrict__ T, const float* __restrict__ scale,
    unsigned short* __restrict__ Tn) {
  int tok = blockIdx.x;
  int t = threadIdx.x;
  const float4* row = (const float4*)(T + (size_t)tok * D_DIM);
  float4 v = row[t];
  float ss = v.x*v.x + v.y*v.y + v.z*v.z + v.w*v.w;
  #pragma unroll
  for (int off = 32; off > 0; off >>= 1) ss += __shfl_down(ss, off);
  __shared__ float part[4];
  if ((t & 63) == 0) part[t >> 6] = ss;
  __syncthreads();
  float total = part[0] + part[1] + part[2] + part[3];
  float rinv = rsqrtf(total * (1.0f / D_DIM) + 1e-6f);
  const float4* sc4 = (const float4*)scale;
  float4 s = sc4[t];
  ushort4 o;
  o.x = f2bf(v.x * rinv * s.x); o.y = f2bf(v.y * rinv * s.y);
  o.z = f2bf(v.z * rinv * s.z); o.w = f2bf(v.w * rinv * s.w);
  ((ushort4*)(Tn + (size_t)tok * D_DIM))[t] = o;
}

// ---------------- fp32 -> bf16 convert ----------------
__global__ __launch_bounds__(256) void f2bf_vec_kernel(
    const float* __restrict__ in, unsigned short* __restrict__ out, int n4) {
  int i = blockIdx.x * 256 + threadIdx.x;
  if (i < n4) {
    float4 v = ((const float4*)in)[i];
    ushort4 o; o.x = f2bf(v.x); o.y = f2bf(v.y); o.z = f2bf(v.z); o.w = f2bf(v.w);
    ((ushort4*)out)[i] = o;
  }
}

// ---------------- prepack SSM weights -> bf16 ----------------
__global__ void prepack_kernel(
    const float* __restrict__ f_win, const float* __restrict__ b_win,
    const float* __restrict__ f_wout, const float* __restrict__ b_wout,
    unsigned short* __restrict__ Wu, unsigned short* __restrict__ Wy) {
  int i = blockIdx.x * blockDim.x + threadIdx.x;
  if (i < 128 * D_DIM) {
    int n = i >> 10, k = i & (D_DIM - 1);
    Wu[i] = f2bf((n < 64) ? f_win[n * D_DIM + k] : b_win[(n - 64) * D_DIM + k]);
    int d = i >> 7, kk = i & 127;
    Wy[i] = f2bf((kk < 64) ? f_wout[d * 64 + kk] : b_wout[d * 64 + (kk - 64)]);
  }
}

// ---------------- bf16 MFMA GEMM: C = A @ Bw^T (+epilogue) ----------------
template<int MODE, typename OUT_T>
__global__ __launch_bounds__(256) void gemm_mfma_kernel(
    const unsigned short* __restrict__ A, const unsigned short* __restrict__ Bw,
    const float* __restrict__ bias, OUT_T* __restrict__ out,
    int M, int N, int Kt,
    const float* __restrict__ aux0, float* __restrict__ aux1) {
  __shared__ unsigned short As[128 * 32];
  __shared__ unsigned short Bs[128 * 32];
  int tid = threadIdx.x;
  int wave = tid >> 6, lane = tid & 63;
  int quad = lane >> 4, lrow = lane & 15;
  int bm = blockIdx.x * 128, bn = blockIdx.y * 128;
  int wm = (wave & 1) * 64, wn = (wave >> 1) * 64;

  int r0 = tid >> 2;
  int c8 = (tid & 3) * 8;
  const unsigned short* Ag0 = A  + (size_t)(bm + r0) * Kt + c8;
  const unsigned short* Ag1 = A  + (size_t)(bm + 64 + r0) * Kt + c8;
  const unsigned short* Bg0 = Bw + (size_t)(bn + r0) * Kt + c8;
  const unsigned short* Bg1 = Bw + (size_t)(bn + 64 + r0) * Kt + c8;
  unsigned short* Al0 = As + (size_t)(wave * 64) * 8;
  unsigned short* Al1 = As + (size_t)(256 + wave * 64) * 8;
  unsigned short* Bl0 = Bs + (size_t)(wave * 64) * 8;
  unsigned short* Bl1 = Bs + (size_t)(256 + wave * 64) * 8;

  floatx4 acc[4][4] = {};
  for (int k0 = 0; k0 < Kt; k0 += 32) {
    load_lds16(Ag0 + k0, Al0);
    load_lds16(Ag1 + k0, Al1);
    load_lds16(Bg0 + k0, Bl0);
    load_lds16(Bg1 + k0, Bl1);
    __syncthreads();
    bf16x8 af[4], bfr[4];
    #pragma unroll
    for (int mi = 0; mi < 4; ++mi)
      af[mi] = *(const bf16x8*)(As + (wm + mi * 16 + lrow) * 32 + quad * 8);
    #pragma unroll
    for (int ni = 0; ni < 4; ++ni)
      bfr[ni] = *(const bf16x8*)(Bs + (wn + ni * 16 + lrow) * 32 + quad * 8);
    #pragma unroll
    for (int mi = 0; mi < 4; ++mi)
      #pragma unroll
      for (int ni = 0; ni < 4; ++ni)
        acc[mi][ni] = __builtin_amdgcn_mfma_f32_16x16x32_bf16(
            af[mi], bfr[ni], acc[mi][ni], 0, 0, 0);
    __syncthreads();
  }

  #pragma unroll
  for (int mi = 0; mi < 4; ++mi) {
    #pragma unroll
    for (int ni = 0; ni < 4; ++ni) {
      #pragma unroll
      for (int r = 0; r < 4; ++r) {
        int m = bm + wm + mi * 16 + quad * 4 + r;
        int n = bn + wn + ni * 16 + lrow;
        float v = acc[mi][ni][r];
        if (MODE == 0) {
          if (bias) v += bias[n];
          if (sizeof(OUT_T) == 2) out[(size_t)m * N + n] = (OUT_T)f2bf(v);
          else                    out[(size_t)m * N + n] = (OUT_T)v;
        } else if (MODE == 1) {
          if (bias) v += bias[n];
          if (n < D_DIM) ((unsigned short*)out)[(size_t)m * D_DIM + n] = f2bf(v);
          else aux1[(size_t)m * D_DIM + (n - D_DIM)] = 1.0f / (1.0f + expf(-v));
        } else if (MODE == 2) {
          v *= aux0[(size_t)m * N + n];
          ((unsigned short*)out)[(size_t)m * N + n] = f2bf(v);
        } else {
          if (bias) v += bias[n];
          v += aux0[(size_t)m * N + n];
          ((float*)out)[(size_t)m * N + n] = v;
        }
      }
    }
  }
}

// ---------------- depthwise conv1d K=3 ----------------
__global__ __launch_bounds__(256) void dwconv_kernel(
    const unsigned short* __restrict__ x, const float* __restrict__ w,
    const float* __restrict__ b, unsigned short* __restrict__ out) {
  size_t i8 = (size_t)blockIdx.x * 256 + threadIdx.x;
  int d8 = (int)(i8 & (D_DIM / 8 - 1));
  size_t tok = i8 >> 7;
  int l = (int)(tok & (L_SEQ - 1));
  int d0 = d8 * 8;
  size_t base = tok * D_DIM + d0;
  bf16x8 cur = *(const bf16x8*)(x + base);
  float acc[8];
  #pragma unroll
  for (int j = 0; j < 8; ++j) {
    int d = d0 + j;
    acc[j] = b[d] + w[d * 3 + 1] * bf2f((unsigned short)cur[j]);
  }
  if (l > 0) {
    bf16x8 prv = *(const bf16x8*)(x + base - D_DIM);
    #pragma unroll
    for (int j = 0; j < 8; ++j) acc[j] += w[(d0 + j) * 3 + 0] * bf2f((unsigned short)prv[j]);
  }
  if (l < L_SEQ - 1) {
    bf16x8 nxt = *(const bf16x8*)(x + base + D_DIM);
    #pragma unroll
    for (int j = 0; j < 8; ++j) acc[j] += w[(d0 + j) * 3 + 2] * bf2f((unsigned short)nxt[j]);
  }
  bf16x8 o;
  #pragma unroll
  for (int j = 0; j < 8; ++j) o[j] = (short)f2bf(acc[j]);
  *(bf16x8*)(out + base) = o;
}

// ---------------- SSM params helper ----------------
__device__ inline void ssm_params(
    int col,
    const float* f_logA, const float* f_B, const float* f_C, const float* f_logdt,
    const float* b_logA, const float* b_B, const float* b_C, const float* b_logdt,
    float& Abar, float& Bbar, float& Cc, float& Aa, float& dt) {
  int dir = col >> 6, n = col & 63;
  const float* logA  = dir ? b_logA  : f_logA;
  const float* Bp    = dir ? b_B     : f_B;
  const float* Cp    = dir ? b_C     : f_C;
  const float* logdt = dir ? b_logdt : f_logdt;
  dt = expf(logdt[0]);
  Aa = -expf(logA[n]);
  Abar = expf(Aa * dt);
  float frac = (fabsf(Aa) < 1e-6f) ? dt : (Abar - 1.0f) / Aa;
  Bbar = frac * Bp[n];
  Cc = Cp[n];
}

// ---------------- scan S1: per-chunk local end-states ----------------
// grid (CHUNKS, B_SZ) x 128 threads; col = tid (0..63 fwd, 64..127 bwd)
__global__ __launch_bounds__(128) void scan_s1_kernel(
    const float* __restrict__ u, float* __restrict__ states,
    const float* __restrict__ f_logA, const float* __restrict__ f_B,
    const float* __restrict__ f_C, const float* __restrict__ f_logdt,
    const float* __restrict__ b_logA, const float* __restrict__ b_B,
    const float* __restrict__ b_C, const float* __restrict__ b_logdt) {
  int col = threadIdx.x;
  int chunk = blockIdx.x, b = blockIdx.y;
  float Abar, Bbar, Cc, Aa, dt;
  ssm_params(col, f_logA, f_B, f_C, f_logdt, b_logA, b_B, b_C, b_logdt,
             Abar, Bbar, Cc, Aa, dt);
  size_t base = ((size_t)b * L_SEQ + (size_t)chunk * CLEN) * 128 + col;
  float h = 0.0f;
  if (col < 64) {
    for (int i0 = 0; i0 < CLEN; i0 += 8) {
      float uv[8];
      #pragma unroll
      for (int j = 0; j < 8; ++j) uv[j] = u[base + (size_t)(i0 + j) * 128];
      #pragma unroll
      for (int j = 0; j < 8; ++j) h = h * Abar + uv[j] * Bbar;
    }
  } else {
    for (int i0 = CLEN - 1; i0 >= 0; i0 -= 8) {
      float uv[8];
      #pragma unroll
      for (int j = 0; j < 8; ++j) uv[j] = u[base + (size_t)(i0 - j) * 128];
      #pragma unroll
      for (int j = 0; j < 8; ++j) h = h * Abar + uv[j] * Bbar;
    }
  }
  states[((size_t)b * CHUNKS + chunk) * 128 + col] = h;
}

// ---------------- scan S2: carries across chunks ----------------
// 1 block x 512 threads: tid -> b = tid>>7, col = tid&127
__global__ __launch_bounds__(512) void scan_s2_kernel(
    const float* __restrict__ states, float* __restrict__ carries,
    const float* __restrict__ f_logA, const float* __restrict__ f_B,
    const float* __restrict__ f_C, const float* __restrict__ f_logdt,
    const float* __restrict__ b_logA, const float* __restrict__ b_B,
    const float* __restrict__ b_C, const float* __restrict__ b_logdt) {
  int tid = threadIdx.x;
  int b = tid >> 7, col = tid & 127;
  float Abar, Bbar, Cc, Aa, dt;
  ssm_params(col, f_logA, f_B, f_C, f_logdt, b_logA, b_B, b_C, b_logdt,
             Abar, Bbar, Cc, Aa, dt);
  float Ac = expf(Aa * dt * (float)CLEN);   // Abar^CLEN
  size_t sb = (size_t)b * CHUNKS * 128 + col;
  float cur = 0.0f;
  if (col < 64) {
    for (int c = 0; c < CHUNKS; ++c) {
      carries[sb + (size_t)c * 128] = cur;
      cur = cur * Ac + states[sb + (size_t)c * 128];
    }
  } else {
    for (int c = CHUNKS - 1; c >= 0; --c) {
      carries[sb + (size_t)c * 128] = cur;
      cur = cur * Ac + states[sb + (size_t)c * 128];
    }
  }
}

// ---------------- scan S3: re-scan with carry, write y (bf16) ----------------
__global__ __launch_bounds__(128) void scan_s3_kernel(
    const float* __restrict__ u, const float* __restrict__ carries,
    unsigned short* __restrict__ y,
    const float* __restrict__ f_logA, const float* __restrict__ f_B,
    const float* __restrict__ f_C, const float* __restrict__ f_logdt,
    const float* __restrict__ b_logA, const float* __restrict__ b_B,
    const float* __restrict__ b_C, const float* __restrict__ b_logdt) {
  int col = threadIdx.x;
  int chunk = blockIdx.x, b = blockIdx.y;
  float Abar, Bbar, Cc, Aa, dt;
  ssm_params(col, f_logA, f_B, f_C, f_logdt, b_logA, b_B, b_C, b_logdt,
             Abar, Bbar, Cc, Aa, dt);
  size_t base = ((size_t)b * L_SEQ + (size_t)chunk * CLEN) * 128 + col;
  float h = carries[((size_t)b * CHUNKS + chunk) * 128 + col];
  if (col < 64) {
    for (int i0 = 0; i0 < CLEN; i0 += 8) {
      float uv[8];
      #pragma unroll
      for (int j = 0; j < 8; ++j) uv[j] = u[base + (size_t)(i0 + j) * 128];
      #pragma unroll
      for (int j = 0; j < 8; ++j) {
        h = h * Abar + uv[j] * Bbar;
        y[base + (size_t)(i0 + j) * 128] = f2bf(h * Cc);
      }
    }
  } else {
    for (int i0 = CLEN - 1; i0 >= 0; i0 -= 8) {
      float uv[8];
      #pragma unroll
      for (int j = 0; j < 8; ++j) uv[j] = u[base + (size_t)(i0 - j) * 128];
      #pragma unroll
      for (int j = 0; j < 8; ++j) {
        h = h * Abar + uv[j] * Bbar;
        y[base + (size_t)(i0 - j) * 128] = f2bf(h * Cc);
      }
    }
  }
}

extern "C" void kernel_launch(void* const* d_in, const int* in_sizes, int n_in,
                              void* d_out, int out_size, void* d_ws, size_t ws_size,
                              hipStream_t stream) {
  const float* T         = (const float*)d_in[0];
  const float* norm_scale= (const float*)d_in[1];
  const float* in_w      = (const float*)d_in[2];
  const float* in_b      = (const float*)d_in[3];
  const float* dw_w      = (const float*)d_in[4];
  const float* dw_b      = (const float*)d_in[5];
  const float* pw_w      = (const float*)d_in[6];
  const float* pw_b      = (const float*)d_in[7];
  const float* f_win     = (const float*)d_in[8];
  const float* f_wout    = (const float*)d_in[9];
  const float* f_logA    = (const float*)d_in[10];
  const float* f_B       = (const float*)d_in[11];
  const float* f_C       = (const float*)d_in[12];
  const float* f_logdt   = (const float*)d_in[13];
  const float* b_win     = (const float*)d_in[14];
  const float* b_wout    = (const float*)d_in[15];
  const float* b_logA    = (const float*)d_in[16];
  const float* b_B       = (const float*)d_in[17];
  const float* b_C       = (const float*)d_in[18];
  const float* b_logdt   = (const float*)d_in[19];
  const float* out_w     = (const float*)d_in[20];
  const float* out_b     = (const float*)d_in[21];
  float* out = (float*)d_out;

  char* ws = (char*)d_ws;
  const size_t MD = (size_t)M_TOK * D_DIM;
  float*          gate  = (float*)ws;                       ws += MD * 4;
  unsigned short* bufA  = (unsigned short*)ws;              ws += MD * 2;
  unsigned short* bufB  = (unsigned short*)ws;              ws += MD * 2;
  float*          u     = (float*)ws;                       ws += (size_t)M_TOK * 128 * 4;
  unsigned short* ybuf  = (unsigned short*)ws;              ws += (size_t)M_TOK * 128 * 2;
  unsigned short* w_in  = (unsigned short*)ws;              ws += (size_t)2 * D_DIM * D_DIM * 2;
  unsigned short* w_pw  = (unsigned short*)ws;              ws += (size_t)D_DIM * D_DIM * 2;
  unsigned short* w_out = (unsigned short*)ws;              ws += (size_t)D_DIM * D_DIM * 2;
  unsigned short* Wu    = (unsigned short*)ws;              ws += (size_t)128 * D_DIM * 2;
  unsigned short* Wy    = (unsigned short*)ws;              ws += (size_t)128 * D_DIM * 2;
  float*          states= (float*)ws;                       ws += (size_t)B_SZ * CHUNKS * 128 * 4;
  float*          carries=(float*)ws;

  // 0. weight conversion / prepack
  f2bf_vec_kernel<<<(2 * D_DIM * D_DIM / 4 + 255) / 256, 256, 0, stream>>>(in_w, w_in, 2 * D_DIM * D_DIM / 4);
  f2bf_vec_kernel<<<(D_DIM * D_DIM / 4 + 255) / 256, 256, 0, stream>>>(pw_w, w_pw, D_DIM * D_DIM / 4);
  f2bf_vec_kernel<<<(D_DIM * D_DIM / 4 + 255) / 256, 256, 0, stream>>>(out_w, w_out, D_DIM * D_DIM / 4);
  prepack_kernel<<<(128 * D_DIM) / 256, 256, 0, stream>>>(f_win, b_win, f_wout, b_wout, Wu, Wy);
  // 1. RMSNorm: T -> bufA (bf16)
  rmsnorm_kernel<<<M_TOK, 256, 0, stream>>>(T, norm_scale, bufA);
  // 2. in_linear: bufA @ w_in^T + in_b -> x(bufB bf16), gate(f32)
  {
    dim3 g(M_TOK / 128, (2 * D_DIM) / 128);
    gemm_mfma_kernel<1, unsigned short><<<g, 256, 0, stream>>>(
        bufA, w_in, in_b, bufB, M_TOK, 2 * D_DIM, D_DIM, nullptr, gate);
  }
  // 3. depthwise conv: bufB -> bufA
  dwconv_kernel<<<(MD / 8) / 256, 256, 0, stream>>>(bufB, dw_w, dw_b, bufA);
  // 4. pointwise: bufA @ w_pw^T + pw_b -> bufB (x_conv bf16)
  {
    dim3 g(M_TOK / 128, D_DIM / 128);
    gemm_mfma_kernel<0, unsigned short><<<g, 256, 0, stream>>>(
        bufA, w_pw, pw_b, bufB, M_TOK, D_DIM, D_DIM, nullptr, nullptr);
  }
  // 5. SSM in-proj: bufB @ Wu^T -> u (f32, M x 128)
  {
    dim3 g(M_TOK / 128, 1);
    gemm_mfma_kernel<0, float><<<g, 256, 0, stream>>>(
        bufB, Wu, nullptr, u, M_TOK, 128, D_DIM, nullptr, nullptr);
  }
  // 6. chunked bidirectional scan: u -> ybuf (bf16)
  {
    dim3 g1(CHUNKS, B_SZ);
    scan_s1_kernel<<<g1, 128, 0, stream>>>(u, states, f_logA, f_B, f_C, f_logdt,
                                           b_logA, b_B, b_C, b_logdt);
    scan_s2_kernel<<<1, 512, 0, stream>>>(states, carries, f_logA, f_B, f_C, f_logdt,
                                          b_logA, b_B, b_C, b_logdt);
    scan_s3_kernel<<<g1, 128, 0, stream>>>(u, carries, ybuf, f_logA, f_B, f_C, f_logdt,
                                           b_logA, b_B, b_C, b_logdt);
  }
  // 7. SSM out-proj + gate: ybuf @ Wy^T * gate -> bufA (bf16)
  {
    dim3 g(M_TOK / 128, D_DIM / 128);
    gemm_mfma_kernel<2, unsigned short><<<g, 256, 0, stream>>>(
        ybuf, Wy, nullptr, bufA, M_TOK, D_DIM, 128, gate, nullptr);
  }
  // 8. out_linear + residual: bufA @ w_out^T + out_b + T -> out (f32)
  {
    dim3 g(M_TOK / 128, D_DIM / 128);
    gemm_mfma_kernel<3, float><<<g, 256, 0, stream>>>(
        bufA, w_out, out_b, out, M_TOK, D_DIM, D_DIM, T, nullptr);
  }
}

// Round 4
// 636.859 us; speedup vs baseline: 4.9040x; 1.0096x over previous
//
#include <hip/hip_runtime.h>
#include <cstdint>

// ViMBlock bf16-MFMA + chunked parallel scan. B=4, L=4096, D=1024, N=64, K=3.
// R4: GEMM K-unroll x2 (one barrier per K=64, 32 MFMA/barrier), grid x=N-tile
// for L2 reuse, gate stored bf16.

#define L_SEQ 4096
#define D_DIM 1024
#define B_SZ 4
#define M_TOK (B_SZ * L_SEQ)   // 16384 tokens
#define CHUNKS 64
#define CLEN (L_SEQ / CHUNKS)  // 64

typedef short bf16x8 __attribute__((ext_vector_type(8)));
typedef float floatx4 __attribute__((ext_vector_type(4)));

__device__ inline unsigned short f2bf(float f) {
  union { float f; unsigned int u; } v; v.f = f;
  unsigned int r = v.u + 0x7FFFu + ((v.u >> 16) & 1u);
  return (unsigned short)(r >> 16);
}
__device__ inline float bf2f(unsigned short h) {
  union { unsigned int u; float f; } v; v.u = ((unsigned int)h) << 16;
  return v.f;
}

__device__ inline void load_lds16(const unsigned short* g, unsigned short* l) {
  __builtin_amdgcn_global_load_lds(
      (const __attribute__((address_space(1))) unsigned int*)g,
      (__attribute__((address_space(3))) unsigned int*)l, 16, 0, 0);
}

// ---------------- RMSNorm: fp32 in -> bf16 out ----------------
__global__ __launch_bounds__(256) void rmsnorm_kernel(
    const float* __restrict__ T, const float* __restrict__ scale,
    unsigned short* __restrict__ Tn) {
  int tok = blockIdx.x;
  int t = threadIdx.x;
  const float4* row = (const float4*)(T + (size_t)tok * D_DIM);
  float4 v = row[t];
  float ss = v.x*v.x + v.y*v.y + v.z*v.z + v.w*v.w;
  #pragma unroll
  for (int off = 32; off > 0; off >>= 1) ss += __shfl_down(ss, off);
  __shared__ float part[4];
  if ((t & 63) == 0) part[t >> 6] = ss;
  __syncthreads();
  float total = part[0] + part[1] + part[2] + part[3];
  float rinv = rsqrtf(total * (1.0f / D_DIM) + 1e-6f);
  const float4* sc4 = (const float4*)scale;
  float4 s = sc4[t];
  ushort4 o;
  o.x = f2bf(v.x * rinv * s.x); o.y = f2bf(v.y * rinv * s.y);
  o.z = f2bf(v.z * rinv * s.z); o.w = f2bf(v.w * rinv * s.w);
  ((ushort4*)(Tn + (size_t)tok * D_DIM))[t] = o;
}

// ---------------- fp32 -> bf16 convert ----------------
__global__ __launch_bounds__(256) void f2bf_vec_kernel(
    const float* __restrict__ in, unsigned short* __restrict__ out, int n4) {
  int i = blockIdx.x * 256 + threadIdx.x;
  if (i < n4) {
    float4 v = ((const float4*)in)[i];
    ushort4 o; o.x = f2bf(v.x); o.y = f2bf(v.y); o.z = f2bf(v.z); o.w = f2bf(v.w);
    ((ushort4*)out)[i] = o;
  }
}

// ---------------- prepack SSM weights -> bf16 ----------------
__global__ void prepack_kernel(
    const float* __restrict__ f_win, const float* __restrict__ b_win,
    const float* __restrict__ f_wout, const float* __restrict__ b_wout,
    unsigned short* __restrict__ Wu, unsigned short* __restrict__ Wy) {
  int i = blockIdx.x * blockDim.x + threadIdx.x;
  if (i < 128 * D_DIM) {
    int n = i >> 10, k = i & (D_DIM - 1);
    Wu[i] = f2bf((n < 64) ? f_win[n * D_DIM + k] : b_win[(n - 64) * D_DIM + k]);
    int d = i >> 7, kk = i & 127;
    Wy[i] = f2bf((kk < 64) ? f_wout[d * 64 + kk] : b_wout[d * 64 + (kk - 64)]);
  }
}

// ---------------- bf16 MFMA GEMM: C = A @ Bw^T (+epilogue) ----------------
// grid: x = N-tile (L2 reuse of A-tile), y = M-tile. 128x128 tile, 256 thr.
// K-loop: 64 per barrier (2 k-slices of 32 into double-width LDS), 32 MFMA.
// MODE 0: out = v (+bias[n])                (OUT_T ushort->bf16 or float)
// MODE 1: N=2048 split: n<1024 -> out(bf16)=v+bias ; else aux1(bf16)=sigmoid(v+bias)
// MODE 2: out(bf16) = v * bf2f(aux0_bf16[m*N+n])    (gate multiply)
// MODE 3: out(f32)  = v + bias[n] + aux0_f32[m*N+n] (residual)
template<int MODE, typename OUT_T>
__global__ __launch_bounds__(256) void gemm_mfma_kernel(
    const unsigned short* __restrict__ A, const unsigned short* __restrict__ Bw,
    const float* __restrict__ bias, OUT_T* __restrict__ out,
    int M, int N, int Kt,
    const void* __restrict__ aux0, unsigned short* __restrict__ aux1) {
  __shared__ unsigned short As[2 * 128 * 32];
  __shared__ unsigned short Bs[2 * 128 * 32];
  int tid = threadIdx.x;
  int wave = tid >> 6, lane = tid & 63;
  int quad = lane >> 4, lrow = lane & 15;
  int bm = blockIdx.y * 128, bn = blockIdx.x * 128;
  int wm = (wave & 1) * 64, wn = (wave >> 1) * 64;

  int r0 = tid >> 2;          // 0..63
  int c8 = (tid & 3) * 8;     // {0,8,16,24}
  const unsigned short* Ag0 = A  + (size_t)(bm + r0) * Kt + c8;
  const unsigned short* Ag1 = A  + (size_t)(bm + 64 + r0) * Kt + c8;
  const unsigned short* Bg0 = Bw + (size_t)(bn + r0) * Kt + c8;
  const unsigned short* Bg1 = Bw + (size_t)(bn + 64 + r0) * Kt + c8;
  // wave-uniform LDS bases (HW adds lane*16B)
  unsigned short* Al0 = As + (size_t)wave * 512;           // rows 0-63, slice 0
  unsigned short* Al1 = As + 2048 + (size_t)wave * 512;    // rows 64-127, slice 0
  unsigned short* Bl0 = Bs + (size_t)wave * 512;
  unsigned short* Bl1 = Bs + 2048 + (size_t)wave * 512;

  floatx4 acc[4][4] = {};
  for (int k0 = 0; k0 < Kt; k0 += 64) {
    load_lds16(Ag0 + k0, Al0);
    load_lds16(Ag1 + k0, Al1);
    load_lds16(Bg0 + k0, Bl0);
    load_lds16(Bg1 + k0, Bl1);
    load_lds16(Ag0 + k0 + 32, Al0 + 4096);
    load_lds16(Ag1 + k0 + 32, Al1 + 4096);
    load_lds16(Bg0 + k0 + 32, Bl0 + 4096);
    load_lds16(Bg1 + k0 + 32, Bl1 + 4096);
    __syncthreads();
    #pragma unroll
    for (int ks = 0; ks < 2; ++ks) {
      const unsigned short* Ab = As + ks * 4096;
      const unsigned short* Bb = Bs + ks * 4096;
      bf16x8 af[4], bfr[4];
      #pragma unroll
      for (int mi = 0; mi < 4; ++mi)
        af[mi] = *(const bf16x8*)(Ab + (wm + mi * 16 + lrow) * 32 + quad * 8);
      #pragma unroll
      for (int ni = 0; ni < 4; ++ni)
        bfr[ni] = *(const bf16x8*)(Bb + (wn + ni * 16 + lrow) * 32 + quad * 8);
      #pragma unroll
      for (int mi = 0; mi < 4; ++mi)
        #pragma unroll
        for (int ni = 0; ni < 4; ++ni)
          acc[mi][ni] = __builtin_amdgcn_mfma_f32_16x16x32_bf16(
              af[mi], bfr[ni], acc[mi][ni], 0, 0, 0);
    }
    __syncthreads();
  }

  // epilogue: C/D layout col=lane&15, row=quad*4+reg  [m89-verified]
  #pragma unroll
  for (int mi = 0; mi < 4; ++mi) {
    #pragma unroll
    for (int ni = 0; ni < 4; ++ni) {
      #pragma unroll
      for (int r = 0; r < 4; ++r) {
        int m = bm + wm + mi * 16 + quad * 4 + r;
        int n = bn + wn + ni * 16 + lrow;
        float v = acc[mi][ni][r];
        if (MODE == 0) {
          if (bias) v += bias[n];
          if (sizeof(OUT_T) == 2) out[(size_t)m * N + n] = (OUT_T)f2bf(v);
          else                    out[(size_t)m * N + n] = (OUT_T)v;
        } else if (MODE == 1) {
          if (bias) v += bias[n];
          if (n < D_DIM) ((unsigned short*)out)[(size_t)m * D_DIM + n] = f2bf(v);
          else aux1[(size_t)m * D_DIM + (n - D_DIM)] = f2bf(1.0f / (1.0f + expf(-v)));
        } else if (MODE == 2) {
          v *= bf2f(((const unsigned short*)aux0)[(size_t)m * N + n]);
          ((unsigned short*)out)[(size_t)m * N + n] = f2bf(v);
        } else {
          if (bias) v += bias[n];
          v += ((const float*)aux0)[(size_t)m * N + n];
          ((float*)out)[(size_t)m * N + n] = v;
        }
      }
    }
  }
}

// ---------------- depthwise conv1d K=3 ----------------
__global__ __launch_bounds__(256) void dwconv_kernel(
    const unsigned short* __restrict__ x, const float* __restrict__ w,
    const float* __restrict__ b, unsigned short* __restrict__ out) {
  size_t i8 = (size_t)blockIdx.x * 256 + threadIdx.x;
  int d8 = (int)(i8 & (D_DIM / 8 - 1));
  size_t tok = i8 >> 7;
  int l = (int)(tok & (L_SEQ - 1));
  int d0 = d8 * 8;
  size_t base = tok * D_DIM + d0;
  bf16x8 cur = *(const bf16x8*)(x + base);
  float acc[8];
  #pragma unroll
  for (int j = 0; j < 8; ++j) {
    int d = d0 + j;
    acc[j] = b[d] + w[d * 3 + 1] * bf2f((unsigned short)cur[j]);
  }
  if (l > 0) {
    bf16x8 prv = *(const bf16x8*)(x + base - D_DIM);
    #pragma unroll
    for (int j = 0; j < 8; ++j) acc[j] += w[(d0 + j) * 3 + 0] * bf2f((unsigned short)prv[j]);
  }
  if (l < L_SEQ - 1) {
    bf16x8 nxt = *(const bf16x8*)(x + base + D_DIM);
    #pragma unroll
    for (int j = 0; j < 8; ++j) acc[j] += w[(d0 + j) * 3 + 2] * bf2f((unsigned short)nxt[j]);
  }
  bf16x8 o;
  #pragma unroll
  for (int j = 0; j < 8; ++j) o[j] = (short)f2bf(acc[j]);
  *(bf16x8*)(out + base) = o;
}

// ---------------- SSM params helper ----------------
__device__ inline void ssm_params(
    int col,
    const float* f_logA, const float* f_B, const float* f_C, const float* f_logdt,
    const float* b_logA, const float* b_B, const float* b_C, const float* b_logdt,
    float& Abar, float& Bbar, float& Cc, float& Aa, float& dt) {
  int dir = col >> 6, n = col & 63;
  const float* logA  = dir ? b_logA  : f_logA;
  const float* Bp    = dir ? b_B     : f_B;
  const float* Cp    = dir ? b_C     : f_C;
  const float* logdt = dir ? b_logdt : f_logdt;
  dt = expf(logdt[0]);
  Aa = -expf(logA[n]);
  Abar = expf(Aa * dt);
  float frac = (fabsf(Aa) < 1e-6f) ? dt : (Abar - 1.0f) / Aa;
  Bbar = frac * Bp[n];
  Cc = Cp[n];
}

// ---------------- scan S1: per-chunk local end-states ----------------
__global__ __launch_bounds__(128) void scan_s1_kernel(
    const float* __restrict__ u, float* __restrict__ states,
    const float* __restrict__ f_logA, const float* __restrict__ f_B,
    const float* __restrict__ f_C, const float* __restrict__ f_logdt,
    const float* __restrict__ b_logA, const float* __restrict__ b_B,
    const float* __restrict__ b_C, const float* __restrict__ b_logdt) {
  int col = threadIdx.x;
  int chunk = blockIdx.x, b = blockIdx.y;
  float Abar, Bbar, Cc, Aa, dt;
  ssm_params(col, f_logA, f_B, f_C, f_logdt, b_logA, b_B, b_C, b_logdt,
             Abar, Bbar, Cc, Aa, dt);
  size_t base = ((size_t)b * L_SEQ + (size_t)chunk * CLEN) * 128 + col;
  float h = 0.0f;
  if (col < 64) {
    for (int i0 = 0; i0 < CLEN; i0 += 8) {
      float uv[8];
      #pragma unroll
      for (int j = 0; j < 8; ++j) uv[j] = u[base + (size_t)(i0 + j) * 128];
      #pragma unroll
      for (int j = 0; j < 8; ++j) h = h * Abar + uv[j] * Bbar;
    }
  } else {
    for (int i0 = CLEN - 1; i0 >= 0; i0 -= 8) {
      float uv[8];
      #pragma unroll
      for (int j = 0; j < 8; ++j) uv[j] = u[base + (size_t)(i0 - j) * 128];
      #pragma unroll
      for (int j = 0; j < 8; ++j) h = h * Abar + uv[j] * Bbar;
    }
  }
  states[((size_t)b * CHUNKS + chunk) * 128 + col] = h;
}

// ---------------- scan S2: carries across chunks ----------------
__global__ __launch_bounds__(512) void scan_s2_kernel(
    const float* __restrict__ states, float* __restrict__ carries,
    const float* __restrict__ f_logA, const float* __restrict__ f_B,
    const float* __restrict__ f_C, const float* __restrict__ f_logdt,
    const float* __restrict__ b_logA, const float* __restrict__ b_B,
    const float* __restrict__ b_C, const float* __restrict__ b_logdt) {
  int tid = threadIdx.x;
  int b = tid >> 7, col = tid & 127;
  float Abar, Bbar, Cc, Aa, dt;
  ssm_params(col, f_logA, f_B, f_C, f_logdt, b_logA, b_B, b_C, b_logdt,
             Abar, Bbar, Cc, Aa, dt);
  float Ac = expf(Aa * dt * (float)CLEN);   // Abar^CLEN
  size_t sb = (size_t)b * CHUNKS * 128 + col;
  float cur = 0.0f;
  if (col < 64) {
    for (int c = 0; c < CHUNKS; ++c) {
      carries[sb + (size_t)c * 128] = cur;
      cur = cur * Ac + states[sb + (size_t)c * 128];
    }
  } else {
    for (int c = CHUNKS - 1; c >= 0; --c) {
      carries[sb + (size_t)c * 128] = cur;
      cur = cur * Ac + states[sb + (size_t)c * 128];
    }
  }
}

// ---------------- scan S3: re-scan with carry, write y (bf16) ----------------
__global__ __launch_bounds__(128) void scan_s3_kernel(
    const float* __restrict__ u, const float* __restrict__ carries,
    unsigned short* __restrict__ y,
    const float* __restrict__ f_logA, const float* __restrict__ f_B,
    const float* __restrict__ f_C, const float* __restrict__ f_logdt,
    const float* __restrict__ b_logA, const float* __restrict__ b_B,
    const float* __restrict__ b_C, const float* __restrict__ b_logdt) {
  int col = threadIdx.x;
  int chunk = blockIdx.x, b = blockIdx.y;
  float Abar, Bbar, Cc, Aa, dt;
  ssm_params(col, f_logA, f_B, f_C, f_logdt, b_logA, b_B, b_C, b_logdt,
             Abar, Bbar, Cc, Aa, dt);
  size_t base = ((size_t)b * L_SEQ + (size_t)chunk * CLEN) * 128 + col;
  float h = carries[((size_t)b * CHUNKS + chunk) * 128 + col];
  if (col < 64) {
    for (int i0 = 0; i0 < CLEN; i0 += 8) {
      float uv[8];
      #pragma unroll
      for (int j = 0; j < 8; ++j) uv[j] = u[base + (size_t)(i0 + j) * 128];
      #pragma unroll
      for (int j = 0; j < 8; ++j) {
        h = h * Abar + uv[j] * Bbar;
        y[base + (size_t)(i0 + j) * 128] = f2bf(h * Cc);
      }
    }
  } else {
    for (int i0 = CLEN - 1; i0 >= 0; i0 -= 8) {
      float uv[8];
      #pragma unroll
      for (int j = 0; j < 8; ++j) uv[j] = u[base + (size_t)(i0 - j) * 128];
      #pragma unroll
      for (int j = 0; j < 8; ++j) {
        h = h * Abar + uv[j] * Bbar;
        y[base + (size_t)(i0 - j) * 128] = f2bf(h * Cc);
      }
    }
  }
}

extern "C" void kernel_launch(void* const* d_in, const int* in_sizes, int n_in,
                              void* d_out, int out_size, void* d_ws, size_t ws_size,
                              hipStream_t stream) {
  const float* T         = (const float*)d_in[0];
  const float* norm_scale= (const float*)d_in[1];
  const float* in_w      = (const float*)d_in[2];
  const float* in_b      = (const float*)d_in[3];
  const float* dw_w      = (const float*)d_in[4];
  const float* dw_b      = (const float*)d_in[5];
  const float* pw_w      = (const float*)d_in[6];
  const float* pw_b      = (const float*)d_in[7];
  const float* f_win     = (const float*)d_in[8];
  const float* f_wout    = (const float*)d_in[9];
  const float* f_logA    = (const float*)d_in[10];
  const float* f_B       = (const float*)d_in[11];
  const float* f_C       = (const float*)d_in[12];
  const float* f_logdt   = (const float*)d_in[13];
  const float* b_win     = (const float*)d_in[14];
  const float* b_wout    = (const float*)d_in[15];
  const float* b_logA    = (const float*)d_in[16];
  const float* b_B       = (const float*)d_in[17];
  const float* b_C       = (const float*)d_in[18];
  const float* b_logdt   = (const float*)d_in[19];
  const float* out_w     = (const float*)d_in[20];
  const float* out_b     = (const float*)d_in[21];
  float* out = (float*)d_out;

  char* ws = (char*)d_ws;
  const size_t MD = (size_t)M_TOK * D_DIM;
  unsigned short* gate  = (unsigned short*)ws;              ws += MD * 2;
  unsigned short* bufA  = (unsigned short*)ws;              ws += MD * 2;
  unsigned short* bufB  = (unsigned short*)ws;              ws += MD * 2;
  float*          u     = (float*)ws;                       ws += (size_t)M_TOK * 128 * 4;
  unsigned short* ybuf  = (unsigned short*)ws;              ws += (size_t)M_TOK * 128 * 2;
  unsigned short* w_in  = (unsigned short*)ws;              ws += (size_t)2 * D_DIM * D_DIM * 2;
  unsigned short* w_pw  = (unsigned short*)ws;              ws += (size_t)D_DIM * D_DIM * 2;
  unsigned short* w_out = (unsigned short*)ws;              ws += (size_t)D_DIM * D_DIM * 2;
  unsigned short* Wu    = (unsigned short*)ws;              ws += (size_t)128 * D_DIM * 2;
  unsigned short* Wy    = (unsigned short*)ws;              ws += (size_t)128 * D_DIM * 2;
  float*          states= (float*)ws;                       ws += (size_t)B_SZ * CHUNKS * 128 * 4;
  float*          carries=(float*)ws;

  // 0. weight conversion / prepack
  f2bf_vec_kernel<<<(2 * D_DIM * D_DIM / 4 + 255) / 256, 256, 0, stream>>>(in_w, w_in, 2 * D_DIM * D_DIM / 4);
  f2bf_vec_kernel<<<(D_DIM * D_DIM / 4 + 255) / 256, 256, 0, stream>>>(pw_w, w_pw, D_DIM * D_DIM / 4);
  f2bf_vec_kernel<<<(D_DIM * D_DIM / 4 + 255) / 256, 256, 0, stream>>>(out_w, w_out, D_DIM * D_DIM / 4);
  prepack_kernel<<<(128 * D_DIM) / 256, 256, 0, stream>>>(f_win, b_win, f_wout, b_wout, Wu, Wy);
  // 1. RMSNorm: T -> bufA (bf16)
  rmsnorm_kernel<<<M_TOK, 256, 0, stream>>>(T, norm_scale, bufA);
  // 2. in_linear: bufA @ w_in^T + in_b -> x(bufB bf16), gate(bf16)
  {
    dim3 g((2 * D_DIM) / 128, M_TOK / 128);
    gemm_mfma_kernel<1, unsigned short><<<g, 256, 0, stream>>>(
        bufA, w_in, in_b, bufB, M_TOK, 2 * D_DIM, D_DIM, nullptr, gate);
  }
  // 3. depthwise conv: bufB -> bufA
  dwconv_kernel<<<(MD / 8) / 256, 256, 0, stream>>>(bufB, dw_w, dw_b, bufA);
  // 4. pointwise: bufA @ w_pw^T + pw_b -> bufB (x_conv bf16)
  {
    dim3 g(D_DIM / 128, M_TOK / 128);
    gemm_mfma_kernel<0, unsigned short><<<g, 256, 0, stream>>>(
        bufA, w_pw, pw_b, bufB, M_TOK, D_DIM, D_DIM, nullptr, nullptr);
  }
  // 5. SSM in-proj: bufB @ Wu^T -> u (f32, M x 128)
  {
    dim3 g(1, M_TOK / 128);
    gemm_mfma_kernel<0, float><<<g, 256, 0, stream>>>(
        bufB, Wu, nullptr, u, M_TOK, 128, D_DIM, nullptr, nullptr);
  }
  // 6. chunked bidirectional scan: u -> ybuf (bf16)
  {
    dim3 g1(CHUNKS, B_SZ);
    scan_s1_kernel<<<g1, 128, 0, stream>>>(u, states, f_logA, f_B, f_C, f_logdt,
                                           b_logA, b_B, b_C, b_logdt);
    scan_s2_kernel<<<1, 512, 0, stream>>>(states, carries, f_logA, f_B, f_C, f_logdt,
                                          b_logA, b_B, b_C, b_logdt);
    scan_s3_kernel<<<g1, 128, 0, stream>>>(u, carries, ybuf, f_logA, f_B, f_C, f_logdt,
                                           b_logA, b_B, b_C, b_logdt);
  }
  // 7. SSM out-proj + gate: ybuf @ Wy^T * gate -> bufA (bf16)
  {
    dim3 g(D_DIM / 128, M_TOK / 128);
    gemm_mfma_kernel<2, unsigned short><<<g, 256, 0, stream>>>(
        ybuf, Wy, nullptr, bufA, M_TOK, D_DIM, 128, gate, nullptr);
  }
  // 8. out_linear + residual: bufA @ w_out^T + out_b + T -> out (f32)
  {
    dim3 g(D_DIM / 128, M_TOK / 128);
    gemm_mfma_kernel<3, float><<<g, 256, 0, stream>>>(
        bufA, w_out, out_b, out, M_TOK, D_DIM, D_DIM, T, nullptr);
  }
}